// Round 6
// baseline (536.630 us; speedup 1.0000x reference)
//
#include <hip/hip_runtime.h>
#include <stdint.h>

// BridgeoutFcLayer forward, training path. Bit-exact vs JAX with
// jax_threefry_partitionable=True (verified: absmax 0.0 in R2-R5):
//   per element i (linear idx over (256,1024,1024)):
//     (b1,b2) = threefry2x32(key=(0,42), hi=0, lo=i);  bits = b1 ^ b2
//     keep <=> MSB(bits)==0
//   w_eff = w + sign_inject(MSB(bits), |w|)
//
// R4/R5 lesson: source-level op "savings" get undone by codegen. This
// revision pins the hash at exactly 138 VALU instructions per element-pair
// via inline asm: two chains (batch b and b+128, same counter +2^27)
// hand-interleaved for 2-way ILP. Only VOP2 adds (literal legal in src0),
// v_alignbit_b32 rotates (inline-const shift), VOP2 xors. Round 1 costs
// 2 ops (v0 := v1-init by SSA), injection 3's "+0" is skipped.
// Everything else is the proven R3 structure (469 us).

// One Threefry round for both chains, r = rotation, sh = 32-r (stringized).
#define TFR2(sh) \
  "v_add_u32 %[a0], %[a0], %[a1]\n\t" \
  "v_add_u32 %[b0], %[b0], %[b1]\n\t" \
  "v_alignbit_b32 %[a1], %[a1], %[a1], " #sh "\n\t" \
  "v_alignbit_b32 %[b1], %[b1], %[b1], " #sh "\n\t" \
  "v_xor_b32 %[a1], %[a1], %[a0]\n\t" \
  "v_xor_b32 %[b1], %[b1], %[b0]\n\t"

// Dual threefry2x32, key (0,42), counters (0,cA) and (0,cB).
// In: a0 = cA + 42, b0 = cB + 42 (v1-state after ks1 injection).
// Out: a0 = w0^w1 for cA, b0 = w0^w1 for cB.
__device__ __forceinline__ void tf_dual(uint32_t& a0, uint32_t& b0) {
  uint32_t a1, b1;
  asm(// round 1: v0 = v1init; v1 = rotl(v1init,13) ^ v1init   (13 -> 19)
      "v_alignbit_b32 %[a1], %[a0], %[a0], 19\n\t"
      "v_alignbit_b32 %[b1], %[b0], %[b0], 19\n\t"
      "v_xor_b32 %[a1], %[a1], %[a0]\n\t"
      "v_xor_b32 %[b1], %[b1], %[b0]\n\t"
      TFR2(17) TFR2(6) TFR2(26)            // rounds 2-4:  r=15,26,6
      // inject (ks1, ks2+1)
      "v_add_u32 %[a0], 42, %[a0]\n\t"
      "v_add_u32 %[b0], 42, %[b0]\n\t"
      "v_add_u32 %[a1], 0x1bd11bf1, %[a1]\n\t"
      "v_add_u32 %[b1], 0x1bd11bf1, %[b1]\n\t"
      TFR2(15) TFR2(3) TFR2(16) TFR2(8)    // rounds 5-8:  r=17,29,16,24
      // inject (ks2, ks0+2)
      "v_add_u32 %[a0], 0x1bd11bf0, %[a0]\n\t"
      "v_add_u32 %[b0], 0x1bd11bf0, %[b0]\n\t"
      "v_add_u32 %[a1], 2, %[a1]\n\t"
      "v_add_u32 %[b1], 2, %[b1]\n\t"
      TFR2(19) TFR2(17) TFR2(6) TFR2(26)   // rounds 9-12: r=13,15,26,6
      // inject (ks0=0 -> skip, ks1+3)
      "v_add_u32 %[a1], 45, %[a1]\n\t"
      "v_add_u32 %[b1], 45, %[b1]\n\t"
      TFR2(15) TFR2(3) TFR2(16) TFR2(8)    // rounds 13-16: r=17,29,16,24
      // inject (ks1, ks2+4)
      "v_add_u32 %[a0], 42, %[a0]\n\t"
      "v_add_u32 %[b0], 42, %[b0]\n\t"
      "v_add_u32 %[a1], 0x1bd11bf4, %[a1]\n\t"
      "v_add_u32 %[b1], 0x1bd11bf4, %[b1]\n\t"
      TFR2(19) TFR2(17) TFR2(6) TFR2(26)   // rounds 17-20: r=13,15,26,6
      // final inject (ks2, ks0+5) + xor-out
      "v_add_u32 %[a0], 0x1bd11bf0, %[a0]\n\t"
      "v_add_u32 %[b0], 0x1bd11bf0, %[b0]\n\t"
      "v_add_u32 %[a1], 5, %[a1]\n\t"
      "v_add_u32 %[b1], 5, %[b1]\n\t"
      "v_xor_b32 %[a0], %[a0], %[a1]\n\t"
      "v_xor_b32 %[b0], %[b0], %[b1]"
      : [a0] "+v"(a0), [b0] "+v"(b0), [a1] "=&v"(a1), [b1] "=&v"(b1));
}

// pert = sign(bits) | |w|  (v_bfi_b32 pattern)
__device__ __forceinline__ float sign_inject(uint32_t bits, float w) {
  uint32_t r = (bits & 0x80000000u) | (__float_as_uint(w) & 0x7FFFFFFFu);
  return __uint_as_float(r);
}

__global__ __launch_bounds__(256) void BridgeoutFcLayer_60413009985793_kernel(
    const float* __restrict__ x, const float* __restrict__ weight,
    const float* __restrict__ bias, float* __restrict__ out) {
  const int oc = blockIdx.x & 3;        // 256-wide output chunk
  const int b  = blockIdx.x >> 2;       // 0..127 (block also does b+128)
  const int o  = (oc << 8) + threadIdx.x;

  // Stage the two x rows; loop reads are wave-uniform LDS broadcasts.
  __shared__ float xs0[1024];
  __shared__ float xs1[1024];
  for (int t = threadIdx.x; t < 1024; t += 256) {
    xs0[t] = x[t + (b << 10)];
    xs1[t] = x[t + ((b + 128) << 10)];
  }
  __syncthreads();

  float acc0 = 0.0f, acc1 = 0.0f;
  const uint32_t cbase0 = ((uint32_t)b << 20) + (uint32_t)o;  // element (b,0,o)
  uint32_t cbase = cbase0;
  const float* wp = weight + o;

#pragma unroll 2
  for (int i = 0; i < 1024; i += 4) {
#pragma unroll 4
    for (int u = 0; u < 4; ++u) {
      float w = wp[u << 10];                                  // shared by b-pair
      // v1-state inits: counter + ks1; single literal add each (compile-folded)
      uint32_t hA = cbase + (uint32_t)((u << 10) + 42);               // (b,     i+u, o)
      uint32_t hB = cbase + (uint32_t)((u << 10) + 42) + 0x08000000u; // (b+128, i+u, o)
      tf_dual(hA, hB);
      acc0 = fmaf(xs0[i + u], w + sign_inject(hA, w), acc0);
      acc1 = fmaf(xs1[i + u], w + sign_inject(hB, w), acc1);
    }
    cbase += 4096u;
    wp += 4096;
  }

  float bo = bias[o];
  out[(b << 10) + o]         = acc0 + bo;
  out[((b + 128) << 10) + o] = acc1 + bo;
}

extern "C" void kernel_launch(void* const* d_in, const int* in_sizes, int n_in,
                              void* d_out, int out_size, void* d_ws, size_t ws_size,
                              hipStream_t stream) {
  const float* x      = (const float*)d_in[0];
  const float* weight = (const float*)d_in[1];
  const float* bias   = (const float*)d_in[2];
  float* out          = (float*)d_out;

  // 128 b-pairs x 4 o-chunks = 512 blocks of 256 threads
  BridgeoutFcLayer_60413009985793_kernel<<<512, 256, 0, stream>>>(x, weight, bias, out);
}

// Round 7
// 518.124 us; speedup vs baseline: 1.0357x; 1.0357x over previous
//
#include <hip/hip_runtime.h>
#include <stdint.h>

// BridgeoutFcLayer forward, training path. Bit-exact vs JAX with
// jax_threefry_partitionable=True (verified: absmax 0.0 in R2-R6):
//   per element i (linear idx over (256,1024,1024)):
//     (b1,b2) = threefry2x32(key=(0,42), hi=0, lo=i);  bits = b1 ^ b2
//     keep <=> MSB(bits)==0
//   w_eff = w + sign_inject(MSB(bits), |w|)
//
// R6 lesson: asm-pinned hash at 2 waves/SIMD regressed (boundary stalls the
// scheduler can't fill). This round: SAME dual-chain asm hash, but one batch
// row per block -> 1024 blocks = 4 waves/SIMD so other waves cover the
// load/FMA tails between asm blocks. Dual chains now = adjacent K elements
// (i, i+1) of the same row (counters differ by 1024). xs reads are one
// ds_read_b128 per 4 elements. w-loads double but are L2-resident (~6 MB
// total fetch, 0.15% HBM).

// One Threefry round for both chains; sh = 32 - rotation (stringized).
#define TFR2(sh) \
  "v_add_u32 %[a0], %[a0], %[a1]\n\t" \
  "v_add_u32 %[b0], %[b0], %[b1]\n\t" \
  "v_alignbit_b32 %[a1], %[a1], %[a1], " #sh "\n\t" \
  "v_alignbit_b32 %[b1], %[b1], %[b1], " #sh "\n\t" \
  "v_xor_b32 %[a1], %[a1], %[a0]\n\t" \
  "v_xor_b32 %[b1], %[b1], %[b0]\n\t"

// Dual threefry2x32, key (0,42), counters (0,cA) and (0,cB).
// In: a0 = cA + 42, b0 = cB + 42. Out: a0 = w0^w1(cA), b0 = w0^w1(cB).
__device__ __forceinline__ void tf_dual(uint32_t& a0, uint32_t& b0) {
  uint32_t a1, b1;
  asm(// round 1: v0 = v1init; v1 = rotl(v1init,13) ^ v1init   (13 -> 19)
      "v_alignbit_b32 %[a1], %[a0], %[a0], 19\n\t"
      "v_alignbit_b32 %[b1], %[b0], %[b0], 19\n\t"
      "v_xor_b32 %[a1], %[a1], %[a0]\n\t"
      "v_xor_b32 %[b1], %[b1], %[b0]\n\t"
      TFR2(17) TFR2(6) TFR2(26)            // rounds 2-4:  r=15,26,6
      "v_add_u32 %[a0], 42, %[a0]\n\t"     // inject (ks1, ks2+1)
      "v_add_u32 %[b0], 42, %[b0]\n\t"
      "v_add_u32 %[a1], 0x1bd11bf1, %[a1]\n\t"
      "v_add_u32 %[b1], 0x1bd11bf1, %[b1]\n\t"
      TFR2(15) TFR2(3) TFR2(16) TFR2(8)    // rounds 5-8:  r=17,29,16,24
      "v_add_u32 %[a0], 0x1bd11bf0, %[a0]\n\t"  // inject (ks2, ks0+2)
      "v_add_u32 %[b0], 0x1bd11bf0, %[b0]\n\t"
      "v_add_u32 %[a1], 2, %[a1]\n\t"
      "v_add_u32 %[b1], 2, %[b1]\n\t"
      TFR2(19) TFR2(17) TFR2(6) TFR2(26)   // rounds 9-12: r=13,15,26,6
      "v_add_u32 %[a1], 45, %[a1]\n\t"     // inject (ks0=0 skip, ks1+3)
      "v_add_u32 %[b1], 45, %[b1]\n\t"
      TFR2(15) TFR2(3) TFR2(16) TFR2(8)    // rounds 13-16: r=17,29,16,24
      "v_add_u32 %[a0], 42, %[a0]\n\t"     // inject (ks1, ks2+4)
      "v_add_u32 %[b0], 42, %[b0]\n\t"
      "v_add_u32 %[a1], 0x1bd11bf4, %[a1]\n\t"
      "v_add_u32 %[b1], 0x1bd11bf4, %[b1]\n\t"
      TFR2(19) TFR2(17) TFR2(6) TFR2(26)   // rounds 17-20: r=13,15,26,6
      "v_add_u32 %[a0], 0x1bd11bf0, %[a0]\n\t"  // final inject (ks2, ks0+5)
      "v_add_u32 %[b0], 0x1bd11bf0, %[b0]\n\t"
      "v_add_u32 %[a1], 5, %[a1]\n\t"
      "v_add_u32 %[b1], 5, %[b1]\n\t"
      "v_xor_b32 %[a0], %[a0], %[a1]\n\t"
      "v_xor_b32 %[b0], %[b0], %[b1]"
      : [a0] "+v"(a0), [b0] "+v"(b0), [a1] "=&v"(a1), [b1] "=&v"(b1));
}

// pert = sign(bits) | |w|  (v_bfi_b32 pattern)
__device__ __forceinline__ float sign_inject(uint32_t bits, float w) {
  uint32_t r = (bits & 0x80000000u) | (__float_as_uint(w) & 0x7FFFFFFFu);
  return __uint_as_float(r);
}

__global__ __launch_bounds__(256) void BridgeoutFcLayer_60413009985793_kernel(
    const float* __restrict__ x, const float* __restrict__ weight,
    const float* __restrict__ bias, float* __restrict__ out) {
  const int oc = blockIdx.x & 3;        // 256-wide output chunk
  const int b  = blockIdx.x >> 2;       // 0..255 (one row per block)
  const int o  = (oc << 8) + threadIdx.x;

  // Stage this block's x row; loop reads are wave-uniform ds_read_b128.
  __shared__ float xs[1024];
  for (int t = threadIdx.x; t < 1024; t += 256) xs[t] = x[t + (b << 10)];
  __syncthreads();

  float acc = 0.0f;
  uint32_t cbase = ((uint32_t)b << 20) + (uint32_t)o;  // element (b, 0, o)
  const float* wp = weight + o;

  for (int i = 0; i < 1024; i += 4) {
    // 4 K-elements per body: one b128 x read, 4 w loads, 2 dual-hash blocks
    float4 x4 = *reinterpret_cast<const float4*>(&xs[i]);
    float w0 = wp[0];
    float w1 = wp[1 << 10];
    float w2 = wp[2 << 10];
    float w3 = wp[3 << 10];

    uint32_t h0 = cbase + 42u;           // counter (b, i+0, o) + ks1
    uint32_t h1 = cbase + (1024u + 42u); // counter (b, i+1, o) + ks1
    uint32_t h2 = cbase + (2048u + 42u);
    uint32_t h3 = cbase + (3072u + 42u);
    tf_dual(h0, h1);
    tf_dual(h2, h3);

    acc = fmaf(x4.x, w0 + sign_inject(h0, w0), acc);
    acc = fmaf(x4.y, w1 + sign_inject(h1, w1), acc);
    acc = fmaf(x4.z, w2 + sign_inject(h2, w2), acc);
    acc = fmaf(x4.w, w3 + sign_inject(h3, w3), acc);

    cbase += 4096u;
    wp += 4096;
  }

  out[(b << 10) + o] = acc + bias[o];
}

extern "C" void kernel_launch(void* const* d_in, const int* in_sizes, int n_in,
                              void* d_out, int out_size, void* d_ws, size_t ws_size,
                              hipStream_t stream) {
  const float* x      = (const float*)d_in[0];
  const float* weight = (const float*)d_in[1];
  const float* bias   = (const float*)d_in[2];
  float* out          = (float*)d_out;

  // 256 rows x 4 o-chunks = 1024 blocks of 256 threads (4 blocks/CU)
  BridgeoutFcLayer_60413009985793_kernel<<<1024, 256, 0, stream>>>(x, weight, bias, out);
}

// Round 8
// 456.910 us; speedup vs baseline: 1.1745x; 1.1340x over previous
//
#include <hip/hip_runtime.h>
#include <stdint.h>

// BridgeoutFcLayer forward, training path. Bit-exact RNG vs JAX with
// jax_threefry_partitionable=True (verified absmax 0.0 in R2-R7):
//   per element i (linear idx over (256,1024,1024)):
//     (b1,b2) = threefry2x32(key=(0,42), hi=0, lo=i);  bits = b1 ^ b2
//     keep <=> MSB(bits)==0;  w_eff = w + sign_inject(MSB(bits), |w|)
//
// R3 (best, 469 us) structure and hot loop KEPT BYTE-IDENTICAL; this round
// only adds K-split x4 TLP (2048 blocks = 32 waves/CU) with atomicAdd
// accumulation. init kernel writes out = bias (also re-inits the poisoned
// buffer each call; same-stream ordering keeps graph replay correct).

__device__ __forceinline__ uint32_t rotl_ab(uint32_t x, uint32_t r) {
  return __builtin_amdgcn_alignbit(x, x, 32u - r);  // rotl == rotr(32-r)
}

#define TF_R(r)                         \
  {                                     \
    v0 += v1;                           \
    v1 = rotl_ab(v1, r) ^ v0;           \
  }

// threefry2x32, key (0,42), counter (0,c); returns word0 ^ word1.
// (Exactly the R3 version - the best-measured codegen.)
__device__ __forceinline__ uint32_t tf_bits_0_42(uint32_t c) {
  const uint32_t KS1 = 42u;
  const uint32_t KS2 = 0x1BD11BF0u;  // 0 ^ 42 ^ 0x1BD11BDA

  uint32_t v1 = c + KS1;   // x2(lo) + ks1
  uint32_t v0 = v1;        // round 1: v0 = 0 + v1 (rename)
  v1 = rotl_ab(v1, 13) ^ v0;
  TF_R(15) TF_R(26) TF_R(6)
  v0 += KS1;               v1 += KS2 + 1u;
  TF_R(17) TF_R(29) TF_R(16) TF_R(24)
  v0 += KS2;               v1 += 2u;            // + ks0 + 2
  TF_R(13) TF_R(15) TF_R(26) TF_R(6)
  /* v0 += ks0 (0) */      v1 += KS1 + 3u;
  TF_R(17) TF_R(29) TF_R(16) TF_R(24)
  v0 += KS1;               v1 += KS2 + 4u;
  TF_R(13) TF_R(15) TF_R(26) TF_R(6)
  v0 += KS2;               v1 += 5u;            // + ks0 + 5
  return v0 ^ v1;
}

// pert = sign(bits) | |w|  (v_bfi_b32 pattern)
__device__ __forceinline__ float sign_inject(uint32_t bits, float w) {
  uint32_t r = (bits & 0x80000000u) | (__float_as_uint(w) & 0x7FFFFFFFu);
  return __uint_as_float(r);
}

__global__ __launch_bounds__(256) void bias_init_kernel(
    const float* __restrict__ bias, float* __restrict__ out) {
  const int idx = blockIdx.x * 256 + threadIdx.x;   // 256K outputs
  out[idx] = bias[idx & 1023];
}

__global__ __launch_bounds__(256) void BridgeoutFcLayer_60413009985793_kernel(
    const float* __restrict__ x, const float* __restrict__ weight,
    float* __restrict__ out) {
  const int oc = blockIdx.x & 3;         // 256-wide output chunk
  const int ks = (blockIdx.x >> 2) & 3;  // K-slice 0..3 (256 K each)
  const int b  = blockIdx.x >> 4;        // 0..127 (block also does b+128)
  const int o  = (oc << 8) + threadIdx.x;
  const int k0 = ks << 8;                // K range [k0, k0+256)

  // Stage the two x row-slices; loop reads are wave-uniform LDS broadcasts.
  __shared__ float xs0[256];
  __shared__ float xs1[256];
  xs0[threadIdx.x] = x[k0 + threadIdx.x + (b << 10)];
  xs1[threadIdx.x] = x[k0 + threadIdx.x + ((b + 128) << 10)];
  __syncthreads();

  float acc0 = 0.0f, acc1 = 0.0f;
  uint32_t cbase = ((uint32_t)b << 20) + ((uint32_t)k0 << 10) + (uint32_t)o;
  const float* wp = weight + (k0 << 10) + o;

#pragma unroll 2
  for (int i = 0; i < 256; i += 4) {
#pragma unroll 4
    for (int u = 0; u < 4; ++u) {
      float w = wp[u << 10];                               // shared by b-pair
      uint32_t bits0 = tf_bits_0_42(cbase + (u << 10));                // (b,     k0+i+u, o)
      uint32_t bits1 = tf_bits_0_42(cbase + (u << 10) + 0x08000000u);  // (b+128, k0+i+u, o)
      acc0 = fmaf(xs0[i + u], w + sign_inject(bits0, w), acc0);
      acc1 = fmaf(xs1[i + u], w + sign_inject(bits1, w), acc1);
    }
    cbase += 4096u;
    wp += 4096;
  }

  atomicAdd(&out[(b << 10) + o], acc0);
  atomicAdd(&out[((b + 128) << 10) + o], acc1);
}

extern "C" void kernel_launch(void* const* d_in, const int* in_sizes, int n_in,
                              void* d_out, int out_size, void* d_ws, size_t ws_size,
                              hipStream_t stream) {
  const float* x      = (const float*)d_in[0];
  const float* weight = (const float*)d_in[1];
  const float* bias   = (const float*)d_in[2];
  float* out          = (float*)d_out;

  // out = bias broadcast (256*1024 elems; also clears harness poison)
  bias_init_kernel<<<1024, 256, 0, stream>>>(bias, out);
  // 128 b-pairs x 4 o-chunks x 4 K-slices = 2048 blocks (8/CU, 32 waves/CU)
  BridgeoutFcLayer_60413009985793_kernel<<<2048, 256, 0, stream>>>(x, weight, out);
}